// Round 1
// baseline (509.011 us; speedup 1.0000x reference)
//
#include <hip/hip_runtime.h>
#include <cmath>

#define LRELU_SLOPE 0.2f

static inline int cdiv_h(int a, int b){ return (a + b - 1) / b; }

__device__ __forceinline__ float dev_lrelu(float x){ return x > 0.f ? x : LRELU_SLOPE * x; }
__device__ __forceinline__ float dev_elu(float x){ return x > 0.f ? x : expm1f(x); }

// ---------------- CSR build (dst-indexed, includes self-loops) ----------------

__global__ void deg_init_kernel(int* __restrict__ rowptr, int n){
  int i = blockIdx.x * blockDim.x + threadIdx.x;
  if (i <= n) rowptr[i] = (i < n) ? 1 : 0;   // 1 = self-loop
}

__global__ void hist_kernel(const int* __restrict__ dst, int e, int* __restrict__ rowptr){
  int i = blockIdx.x * blockDim.x + threadIdx.x;
  if (i < e) atomicAdd(&rowptr[dst[i]], 1);
}

__global__ void scan_blocks_kernel(int* __restrict__ data, int n, int* __restrict__ bsum){
  __shared__ int sd[256];
  int idx = blockIdx.x * 256 + threadIdx.x;
  int v = (idx < n) ? data[idx] : 0;
  sd[threadIdx.x] = v;
  __syncthreads();
  #pragma unroll
  for (int off = 1; off < 256; off <<= 1){
    int x = (threadIdx.x >= off) ? sd[threadIdx.x - off] : 0;
    __syncthreads();
    sd[threadIdx.x] += x;
    __syncthreads();
  }
  if (idx < n) data[idx] = sd[threadIdx.x] - v;   // exclusive
  if (threadIdx.x == 255) bsum[blockIdx.x] = sd[255];
}

__global__ void scan_bsums_kernel(int* __restrict__ bsum, int nb){
  __shared__ int sd[256];
  int v = (threadIdx.x < nb) ? bsum[threadIdx.x] : 0;
  sd[threadIdx.x] = v;
  __syncthreads();
  #pragma unroll
  for (int off = 1; off < 256; off <<= 1){
    int x = (threadIdx.x >= off) ? sd[threadIdx.x - off] : 0;
    __syncthreads();
    sd[threadIdx.x] += x;
    __syncthreads();
  }
  if (threadIdx.x < nb) bsum[threadIdx.x] = sd[threadIdx.x] - v;
}

__global__ void scan_add_kernel(int* __restrict__ data, int n, const int* __restrict__ bsum, int total){
  int idx = blockIdx.x * blockDim.x + threadIdx.x;
  if (idx < n) data[idx] += bsum[idx >> 8];
  if (idx == 0) data[n] = total;
}

__global__ void scatter_kernel(const int* __restrict__ ei, int e, int n,
                               int* __restrict__ cursor, int* __restrict__ col){
  int i = blockIdx.x * blockDim.x + threadIdx.x;
  int tot = e + n;
  if (i >= tot) return;
  int s, d;
  if (i < e){ s = ei[i]; d = ei[e + i]; } else { s = d = i - e; }
  int pos = atomicAdd(&cursor[d], 1);
  col[pos] = s;
}

// ---------------- fp32 tiled GEMM: C[M,N] = A[M,K] @ B[K,N] ----------------
// BM=BN=64, BK=16, 256 threads, 4x4 micro-tile. Requires N%64==0, K%16==0.
template<int BM, int BN, int BK>
__launch_bounds__(256)
__global__ void gemm_kernel(const float* __restrict__ A, const float* __restrict__ B,
                            float* __restrict__ C, int M, int N, int K)
{
  __shared__ float As[BK][BM + 4];   // +4 pad keeps 16B alignment, breaks pow2 stride
  __shared__ float Bs[BK][BN];
  const int tid = threadIdx.x;
  const int bm = blockIdx.x, bn = blockIdx.y;
  const int tm = tid >> 4, tn = tid & 15;
  const int m0 = tm * 4, n0 = tn * 4;
  const int arow = tid >> 2, akq = tid & 3;     // A loader: 64 rows x 4 float4/row
  const int bkr = tid >> 4, bnq = tid & 15;     // B loader: 16 k-rows x 16 float4/row
  const int gm_a = bm * BM + arow;

  float acc[4][4] = {};
  for (int k0 = 0; k0 < K; k0 += BK){
    float4 a4 = make_float4(0.f, 0.f, 0.f, 0.f);
    if (gm_a < M) a4 = *(const float4*)&A[(size_t)gm_a * K + k0 + akq * 4];
    float4 b4 = *(const float4*)&B[(size_t)(k0 + bkr) * N + bn * BN + bnq * 4];
    __syncthreads();
    As[akq * 4 + 0][arow] = a4.x;
    As[akq * 4 + 1][arow] = a4.y;
    As[akq * 4 + 2][arow] = a4.z;
    As[akq * 4 + 3][arow] = a4.w;
    *(float4*)&Bs[bkr][bnq * 4] = b4;
    __syncthreads();
    #pragma unroll
    for (int k = 0; k < BK; k++){
      float av[4], bv[4];
      *(float4*)av = *(const float4*)&As[k][m0];
      *(float4*)bv = *(const float4*)&Bs[k][n0];
      #pragma unroll
      for (int i = 0; i < 4; i++)
        #pragma unroll
        for (int j = 0; j < 4; j++)
          acc[i][j] += av[i] * bv[j];
    }
  }
  #pragma unroll
  for (int i = 0; i < 4; i++){
    int gm = bm * BM + m0 + i;
    if (gm < M){
      float4 o = make_float4(acc[i][0], acc[i][1], acc[i][2], acc[i][3]);
      *(float4*)&C[(size_t)gm * N + bn * BN + n0] = o;
    }
  }
}

// ---------------- attention halves, layer 1 (H=4, C=64) ----------------
// one wave per node; lane l owns channels [4l, 4l+4)
__global__ void es_ed1_kernel(const float* __restrict__ h1,
                              const float* __restrict__ a_src, const float* __restrict__ a_dst,
                              float* __restrict__ es, float* __restrict__ ed, int n)
{
  int node = blockIdx.x * 4 + (threadIdx.x >> 6);
  if (node >= n) return;
  int lane = threadIdx.x & 63;
  int h = lane >> 4;          // head
  int q = lane & 15;          // 16 lanes per head
  float4 v  = *(const float4*)&h1[(size_t)node * 256 + lane * 4];
  float4 as = *(const float4*)&a_src[h * 64 + q * 4];
  float4 ad = *(const float4*)&a_dst[h * 64 + q * 4];
  float ps = v.x * as.x + v.y * as.y + v.z * as.z + v.w * as.w;
  float pd = v.x * ad.x + v.y * ad.y + v.z * ad.z + v.w * ad.w;
  #pragma unroll
  for (int off = 1; off < 16; off <<= 1){
    ps += __shfl_xor(ps, off, 64);
    pd += __shfl_xor(pd, off, 64);
  }
  if (q == 0){ es[node * 4 + h] = ps; ed[node * 4 + h] = pd; }
}

// ---------------- layer-1 aggregation: online softmax, one wave per node ----------------
__global__ void agg1_kernel(const float* __restrict__ h1, const float* __restrict__ es,
                            const float* __restrict__ ed, const int* __restrict__ rowptr,
                            const int* __restrict__ col, const float* __restrict__ b1,
                            float* __restrict__ out1, int n)
{
  int node = blockIdx.x * 4 + (threadIdx.x >> 6);
  if (node >= n) return;
  int lane = threadIdx.x & 63;
  int h = lane >> 4;
  float edh = ed[node * 4 + h];
  int start = rowptr[node], end = rowptr[node + 1];
  float m = -INFINITY, l = 0.f;
  float4 acc = make_float4(0.f, 0.f, 0.f, 0.f);
  for (int j = start; j < end; ++j){
    int s = col[j];
    float logit = dev_lrelu(es[s * 4 + h] + edh);
    float nm = fmaxf(m, logit);
    float sc = __expf(m - nm);       // first iter: exp(-inf) = 0
    float p  = __expf(logit - nm);
    m = nm;
    l = l * sc + p;
    float4 v = *(const float4*)&h1[(size_t)s * 256 + lane * 4];
    acc.x = acc.x * sc + v.x * p;
    acc.y = acc.y * sc + v.y * p;
    acc.z = acc.z * sc + v.z * p;
    acc.w = acc.w * sc + v.w * p;
  }
  float inv = 1.f / (l + 1e-16f);
  float4 bb = *(const float4*)&b1[lane * 4];
  float4 o;
  o.x = dev_elu(acc.x * inv + bb.x);
  o.y = dev_elu(acc.y * inv + bb.y);
  o.z = dev_elu(acc.z * inv + bb.z);
  o.w = dev_elu(acc.w * inv + bb.w);
  *(float4*)&out1[(size_t)node * 256 + lane * 4] = o;
}

// ---------------- attention halves, layer 2 (H=1, C=64) ----------------
__global__ void es_ed2_kernel(const float* __restrict__ h2,
                              const float* __restrict__ a_src, const float* __restrict__ a_dst,
                              float* __restrict__ es, float* __restrict__ ed, int n)
{
  int node = blockIdx.x * 4 + (threadIdx.x >> 6);
  if (node >= n) return;
  int lane = threadIdx.x & 63;
  float v = h2[(size_t)node * 64 + lane];
  float ps = v * a_src[lane];
  float pd = v * a_dst[lane];
  #pragma unroll
  for (int off = 1; off < 64; off <<= 1){
    ps += __shfl_xor(ps, off, 64);
    pd += __shfl_xor(pd, off, 64);
  }
  if (lane == 0){ es[node] = ps; ed[node] = pd; }
}

// ---------------- layer-2 aggregation + ELU + final linear, fused ----------------
__global__ void agg2_kernel(const float* __restrict__ h2, const float* __restrict__ es,
                            const float* __restrict__ ed, const int* __restrict__ rowptr,
                            const int* __restrict__ col, const float* __restrict__ b2,
                            const float* __restrict__ Wo, const float* __restrict__ bo,
                            float* __restrict__ out, int n)
{
  int node = blockIdx.x * 4 + (threadIdx.x >> 6);
  if (node >= n) return;
  int lane = threadIdx.x & 63;
  float edh = ed[node];
  int start = rowptr[node], end = rowptr[node + 1];
  float m = -INFINITY, l = 0.f, acc = 0.f;
  for (int j = start; j < end; ++j){
    int s = col[j];
    float logit = dev_lrelu(es[s] + edh);
    float nm = fmaxf(m, logit);
    float sc = __expf(m - nm);
    float p  = __expf(logit - nm);
    m = nm;
    l = l * sc + p;
    float v = h2[(size_t)s * 64 + lane];
    acc = acc * sc + v * p;
  }
  float y = dev_elu(acc / (l + 1e-16f) + b2[lane]);
  float t = y * Wo[lane];
  #pragma unroll
  for (int off = 1; off < 64; off <<= 1) t += __shfl_xor(t, off, 64);
  if (lane == 0) out[node] = t + bo[0];
}

// ---------------- launch ----------------
extern "C" void kernel_launch(void* const* d_in, const int* in_sizes, int n_in,
                              void* d_out, int out_size, void* d_ws, size_t ws_size,
                              hipStream_t stream)
{
  const float* x    = (const float*)d_in[0];
  const float* W1   = (const float*)d_in[1];
  const float* a_s1 = (const float*)d_in[2];
  const float* a_d1 = (const float*)d_in[3];
  const float* b1   = (const float*)d_in[4];
  const float* W2   = (const float*)d_in[5];
  const float* a_s2 = (const float*)d_in[6];
  const float* a_d2 = (const float*)d_in[7];
  const float* b2   = (const float*)d_in[8];
  const float* Wo   = (const float*)d_in[9];
  const float* bo   = (const float*)d_in[10];
  const int*   ei   = (const int*)d_in[11];

  const int Nn = in_sizes[0] / 128;     // 50000
  const int E  = in_sizes[11] / 2;      // 800000
  const int ET = E + Nn;                // with self-loops

  size_t off = 0;
  auto carve = [&](size_t bytes) -> void* {
    void* p = (char*)d_ws + off;
    off += (bytes + 255) & ~(size_t)255;
    return p;
  };
  float* h1     = (float*)carve((size_t)Nn * 256 * sizeof(float));  // reused as h2 later
  float* out1   = (float*)carve((size_t)Nn * 256 * sizeof(float));
  float* es1    = (float*)carve((size_t)Nn * 4 * sizeof(float));
  float* ed1    = (float*)carve((size_t)Nn * 4 * sizeof(float));
  float* es2    = (float*)carve((size_t)Nn * sizeof(float));
  float* ed2    = (float*)carve((size_t)Nn * sizeof(float));
  int*   rowptr = (int*)carve((size_t)(Nn + 1) * sizeof(int));
  int*   cursor = (int*)carve((size_t)Nn * sizeof(int));
  int*   bsum   = (int*)carve(256 * sizeof(int));
  int*   col    = (int*)carve((size_t)ET * sizeof(int));
  float* h2  = h1;                       // alias: h1 dead before gemm2 writes
  float* out = (float*)d_out;

  // h1 = x @ W1  [Nn,128]x[128,256]
  gemm_kernel<64,64,16><<<dim3(cdiv_h(Nn,64), 256/64), 256, 0, stream>>>(x, W1, h1, Nn, 256, 128);

  // CSR by dst (self-loops included)
  deg_init_kernel<<<cdiv_h(Nn + 1, 256), 256, 0, stream>>>(rowptr, Nn);
  hist_kernel<<<cdiv_h(E, 256), 256, 0, stream>>>(ei + E, E, rowptr);
  int nb = cdiv_h(Nn, 256);              // 196 <= 256
  scan_blocks_kernel<<<nb, 256, 0, stream>>>(rowptr, Nn, bsum);
  scan_bsums_kernel<<<1, 256, 0, stream>>>(bsum, nb);
  scan_add_kernel<<<cdiv_h(Nn, 256), 256, 0, stream>>>(rowptr, Nn, bsum, ET);
  hipMemcpyAsync(cursor, rowptr, (size_t)Nn * sizeof(int), hipMemcpyDeviceToDevice, stream);
  scatter_kernel<<<cdiv_h(ET, 256), 256, 0, stream>>>(ei, E, Nn, cursor, col);

  // layer 1 attention + aggregation + ELU
  es_ed1_kernel<<<cdiv_h(Nn, 4), 256, 0, stream>>>(h1, a_s1, a_d1, es1, ed1, Nn);
  agg1_kernel<<<cdiv_h(Nn, 4), 256, 0, stream>>>(h1, es1, ed1, rowptr, col, b1, out1, Nn);

  // layer 2
  gemm_kernel<64,64,16><<<dim3(cdiv_h(Nn,64), 64/64), 256, 0, stream>>>(out1, W2, h2, Nn, 64, 256);
  es_ed2_kernel<<<cdiv_h(Nn, 4), 256, 0, stream>>>(h2, a_s2, a_d2, es2, ed2, Nn);
  agg2_kernel<<<cdiv_h(Nn, 4), 256, 0, stream>>>(h2, es2, ed2, rowptr, col, b2, Wo, bo, out, Nn);
}

// Round 2
// 404.022 us; speedup vs baseline: 1.2599x; 1.2599x over previous
//
#include <hip/hip_runtime.h>
#include <cmath>

#define LRELU_SLOPE 0.2f

static inline int cdiv_h(int a, int b){ return (a + b - 1) / b; }

__device__ __forceinline__ float dev_lrelu(float x){ return x > 0.f ? x : LRELU_SLOPE * x; }
__device__ __forceinline__ float dev_elu(float x){ return x > 0.f ? x : expm1f(x); }

__device__ __forceinline__ unsigned short f2bf(float f){
  unsigned int u = __float_as_uint(f);
  u = (u + 0x7FFFu + ((u >> 16) & 1u)) >> 16;   // RNE
  return (unsigned short)u;
}
__device__ __forceinline__ float bf2f(unsigned short s){
  return __uint_as_float(((unsigned int)s) << 16);
}

// ---------------- CSR build (dst-indexed, includes self-loops) ----------------

__global__ void deg_init_kernel(int* __restrict__ rowptr, int n){
  int i = blockIdx.x * blockDim.x + threadIdx.x;
  if (i <= n) rowptr[i] = (i < n) ? 1 : 0;   // 1 = self-loop
}

__global__ void hist_kernel(const int* __restrict__ dst, int e, int* __restrict__ rowptr){
  int i = blockIdx.x * blockDim.x + threadIdx.x;
  if (i < e) atomicAdd(&rowptr[dst[i]], 1);
}

__global__ void scan_blocks_kernel(int* __restrict__ data, int n, int* __restrict__ bsum){
  __shared__ int sd[256];
  int idx = blockIdx.x * 256 + threadIdx.x;
  int v = (idx < n) ? data[idx] : 0;
  sd[threadIdx.x] = v;
  __syncthreads();
  #pragma unroll
  for (int off = 1; off < 256; off <<= 1){
    int x = (threadIdx.x >= off) ? sd[threadIdx.x - off] : 0;
    __syncthreads();
    sd[threadIdx.x] += x;
    __syncthreads();
  }
  if (idx < n) data[idx] = sd[threadIdx.x] - v;   // exclusive
  if (threadIdx.x == 255) bsum[blockIdx.x] = sd[255];
}

__global__ void scan_bsums_kernel(int* __restrict__ bsum, int nb){
  __shared__ int sd[256];
  int v = (threadIdx.x < nb) ? bsum[threadIdx.x] : 0;
  sd[threadIdx.x] = v;
  __syncthreads();
  #pragma unroll
  for (int off = 1; off < 256; off <<= 1){
    int x = (threadIdx.x >= off) ? sd[threadIdx.x - off] : 0;
    __syncthreads();
    sd[threadIdx.x] += x;
    __syncthreads();
  }
  if (threadIdx.x < nb) bsum[threadIdx.x] = sd[threadIdx.x] - v;
}

__global__ void scan_add_kernel(int* __restrict__ data, int n, const int* __restrict__ bsum, int total){
  int idx = blockIdx.x * blockDim.x + threadIdx.x;
  if (idx < n) data[idx] += bsum[idx >> 8];
  if (idx == 0) data[n] = total;
}

__global__ void scatter_kernel(const int* __restrict__ ei, int e, int n,
                               int* __restrict__ cursor, int* __restrict__ col){
  int i = blockIdx.x * blockDim.x + threadIdx.x;
  int tot = e + n;
  if (i >= tot) return;
  int s, d;
  if (i < e){ s = ei[i]; d = ei[e + i]; } else { s = d = i - e; }
  int pos = atomicAdd(&cursor[d], 1);
  col[pos] = s;
}

// ---- fp32 tiled GEMM, bf16 output + fused attention-half epilogue ----
// C_bf[M,N] = bf16(A[M,K] @ B[K,N]);  es/ed[node*H + bn] = dot(row, a_src/a_dst[bn])
// BM=BN=64, BK=16, 256 threads, 4x4 micro-tile. N%64==0, K%16==0. head = blockIdx.y.
template<int BM, int BN, int BK>
__launch_bounds__(256)
__global__ void gemm_att_kernel(const float* __restrict__ A, const float* __restrict__ B,
                                unsigned short* __restrict__ Cb,
                                const float* __restrict__ a_src, const float* __restrict__ a_dst,
                                float* __restrict__ es, float* __restrict__ ed,
                                int M, int N, int K, int H)
{
  __shared__ float As[BK][BM + 4];
  __shared__ float Bs[BK][BN];
  const int tid = threadIdx.x;
  const int bm = blockIdx.x, bn = blockIdx.y;
  const int tm = tid >> 4, tn = tid & 15;
  const int m0 = tm * 4, n0 = tn * 4;
  const int arow = tid >> 2, akq = tid & 3;
  const int bkr = tid >> 4, bnq = tid & 15;
  const int gm_a = bm * BM + arow;

  float acc[4][4] = {};
  for (int k0 = 0; k0 < K; k0 += BK){
    float4 a4 = make_float4(0.f, 0.f, 0.f, 0.f);
    if (gm_a < M) a4 = *(const float4*)&A[(size_t)gm_a * K + k0 + akq * 4];
    float4 b4 = *(const float4*)&B[(size_t)(k0 + bkr) * N + bn * BN + bnq * 4];
    __syncthreads();
    As[akq * 4 + 0][arow] = a4.x;
    As[akq * 4 + 1][arow] = a4.y;
    As[akq * 4 + 2][arow] = a4.z;
    As[akq * 4 + 3][arow] = a4.w;
    *(float4*)&Bs[bkr][bnq * 4] = b4;
    __syncthreads();
    #pragma unroll
    for (int k = 0; k < BK; k++){
      float av[4], bv[4];
      *(float4*)av = *(const float4*)&As[k][m0];
      *(float4*)bv = *(const float4*)&Bs[k][n0];
      #pragma unroll
      for (int i = 0; i < 4; i++)
        #pragma unroll
        for (int j = 0; j < 4; j++)
          acc[i][j] += av[i] * bv[j];
    }
  }

  const float4 as4 = *(const float4*)&a_src[bn * 64 + n0];
  const float4 ad4 = *(const float4*)&a_dst[bn * 64 + n0];
  #pragma unroll
  for (int i = 0; i < 4; i++){
    int gm = bm * BM + m0 + i;
    // bf16 store of the tile row-chunk
    if (gm < M){
      ushort4 o;
      o.x = f2bf(acc[i][0]); o.y = f2bf(acc[i][1]);
      o.z = f2bf(acc[i][2]); o.w = f2bf(acc[i][3]);
      *(ushort4*)&Cb[(size_t)gm * N + bn * BN + n0] = o;
    }
    // partial attention dots, reduce across the 16 tn-lanes (contiguous in wave)
    float ps = acc[i][0] * as4.x + acc[i][1] * as4.y + acc[i][2] * as4.z + acc[i][3] * as4.w;
    float pd = acc[i][0] * ad4.x + acc[i][1] * ad4.y + acc[i][2] * ad4.z + acc[i][3] * ad4.w;
    #pragma unroll
    for (int off = 1; off < 16; off <<= 1){
      ps += __shfl_xor(ps, off, 64);
      pd += __shfl_xor(pd, off, 64);
    }
    if (tn == 0 && gm < M){
      es[(size_t)gm * H + bn] = ps;
      ed[(size_t)gm * H + bn] = pd;
    }
  }
}

// ---------------- layer-1 aggregation: online softmax, one wave per node ----------------
// h1b: bf16 [N,256]; lane owns channels [4l,4l+4)
__global__ void agg1_kernel(const unsigned short* __restrict__ h1b, const float* __restrict__ es,
                            const float* __restrict__ ed, const int* __restrict__ rowptr,
                            const int* __restrict__ col, const float* __restrict__ b1,
                            float* __restrict__ out1, int n)
{
  int node = blockIdx.x * 4 + (threadIdx.x >> 6);
  if (node >= n) return;
  int lane = threadIdx.x & 63;
  int h = lane >> 4;
  float edh = ed[node * 4 + h];
  int start = rowptr[node], end = rowptr[node + 1];
  float m = -INFINITY, l = 0.f;
  float4 acc = make_float4(0.f, 0.f, 0.f, 0.f);
  int j = start;
  for (; j + 1 < end; j += 2){
    int s0 = col[j], s1 = col[j + 1];
    float e0 = es[s0 * 4 + h], e1 = es[s1 * 4 + h];
    ushort4 r0 = *(const ushort4*)&h1b[(size_t)s0 * 256 + lane * 4];
    ushort4 r1 = *(const ushort4*)&h1b[(size_t)s1 * 256 + lane * 4];
    float l0 = dev_lrelu(e0 + edh), l1 = dev_lrelu(e1 + edh);
    float nm = fmaxf(m, fmaxf(l0, l1));
    float sc = __expf(m - nm);
    float p0 = __expf(l0 - nm), p1 = __expf(l1 - nm);
    m = nm;
    l = l * sc + p0 + p1;
    acc.x = acc.x * sc + bf2f(r0.x) * p0 + bf2f(r1.x) * p1;
    acc.y = acc.y * sc + bf2f(r0.y) * p0 + bf2f(r1.y) * p1;
    acc.z = acc.z * sc + bf2f(r0.z) * p0 + bf2f(r1.z) * p1;
    acc.w = acc.w * sc + bf2f(r0.w) * p0 + bf2f(r1.w) * p1;
  }
  if (j < end){
    int s0 = col[j];
    float logit = dev_lrelu(es[s0 * 4 + h] + edh);
    ushort4 r0 = *(const ushort4*)&h1b[(size_t)s0 * 256 + lane * 4];
    float nm = fmaxf(m, logit);
    float sc = __expf(m - nm);
    float p  = __expf(logit - nm);
    m = nm;
    l = l * sc + p;
    acc.x = acc.x * sc + bf2f(r0.x) * p;
    acc.y = acc.y * sc + bf2f(r0.y) * p;
    acc.z = acc.z * sc + bf2f(r0.z) * p;
    acc.w = acc.w * sc + bf2f(r0.w) * p;
  }
  float inv = 1.f / (l + 1e-16f);
  float4 bb = *(const float4*)&b1[lane * 4];
  float4 o;
  o.x = dev_elu(acc.x * inv + bb.x);
  o.y = dev_elu(acc.y * inv + bb.y);
  o.z = dev_elu(acc.z * inv + bb.z);
  o.w = dev_elu(acc.w * inv + bb.w);
  *(float4*)&out1[(size_t)node * 256 + lane * 4] = o;
}

// ---------------- layer-2 aggregation + ELU + final linear, fused ----------------
__global__ void agg2_kernel(const unsigned short* __restrict__ h2b, const float* __restrict__ es,
                            const float* __restrict__ ed, const int* __restrict__ rowptr,
                            const int* __restrict__ col, const float* __restrict__ b2,
                            const float* __restrict__ Wo, const float* __restrict__ bo,
                            float* __restrict__ out, int n)
{
  int node = blockIdx.x * 4 + (threadIdx.x >> 6);
  if (node >= n) return;
  int lane = threadIdx.x & 63;
  float edh = ed[node];
  int start = rowptr[node], end = rowptr[node + 1];
  float m = -INFINITY, l = 0.f, acc = 0.f;
  int j = start;
  for (; j + 1 < end; j += 2){
    int s0 = col[j], s1 = col[j + 1];
    float e0 = es[s0], e1 = es[s1];
    unsigned short r0 = h2b[(size_t)s0 * 64 + lane];
    unsigned short r1 = h2b[(size_t)s1 * 64 + lane];
    float l0 = dev_lrelu(e0 + edh), l1 = dev_lrelu(e1 + edh);
    float nm = fmaxf(m, fmaxf(l0, l1));
    float sc = __expf(m - nm);
    float p0 = __expf(l0 - nm), p1 = __expf(l1 - nm);
    m = nm;
    l = l * sc + p0 + p1;
    acc = acc * sc + bf2f(r0) * p0 + bf2f(r1) * p1;
  }
  if (j < end){
    int s0 = col[j];
    float logit = dev_lrelu(es[s0] + edh);
    unsigned short r0 = h2b[(size_t)s0 * 64 + lane];
    float nm = fmaxf(m, logit);
    float sc = __expf(m - nm);
    float p  = __expf(logit - nm);
    m = nm;
    l = l * sc + p;
    acc = acc * sc + bf2f(r0) * p;
  }
  float y = dev_elu(acc / (l + 1e-16f) + b2[lane]);
  float t = y * Wo[lane];
  #pragma unroll
  for (int off = 1; off < 64; off <<= 1) t += __shfl_xor(t, off, 64);
  if (lane == 0) out[node] = t + bo[0];
}

// ---------------- launch ----------------
extern "C" void kernel_launch(void* const* d_in, const int* in_sizes, int n_in,
                              void* d_out, int out_size, void* d_ws, size_t ws_size,
                              hipStream_t stream)
{
  const float* x    = (const float*)d_in[0];
  const float* W1   = (const float*)d_in[1];
  const float* a_s1 = (const float*)d_in[2];
  const float* a_d1 = (const float*)d_in[3];
  const float* b1   = (const float*)d_in[4];
  const float* W2   = (const float*)d_in[5];
  const float* a_s2 = (const float*)d_in[6];
  const float* a_d2 = (const float*)d_in[7];
  const float* b2   = (const float*)d_in[8];
  const float* Wo   = (const float*)d_in[9];
  const float* bo   = (const float*)d_in[10];
  const int*   ei   = (const int*)d_in[11];

  const int Nn = in_sizes[0] / 128;     // 50000
  const int E  = in_sizes[11] / 2;      // 800000
  const int ET = E + Nn;                // with self-loops

  size_t off = 0;
  auto carve = [&](size_t bytes) -> void* {
    void* p = (char*)d_ws + off;
    off += (bytes + 255) & ~(size_t)255;
    return p;
  };
  unsigned short* h1b = (unsigned short*)carve((size_t)Nn * 256 * sizeof(unsigned short));
  float* out1   = (float*)carve((size_t)Nn * 256 * sizeof(float));
  unsigned short* h2b = (unsigned short*)carve((size_t)Nn * 64 * sizeof(unsigned short));
  float* es1    = (float*)carve((size_t)Nn * 4 * sizeof(float));
  float* ed1    = (float*)carve((size_t)Nn * 4 * sizeof(float));
  float* es2    = (float*)carve((size_t)Nn * sizeof(float));
  float* ed2    = (float*)carve((size_t)Nn * sizeof(float));
  int*   rowptr = (int*)carve((size_t)(Nn + 1) * sizeof(int));
  int*   cursor = (int*)carve((size_t)Nn * sizeof(int));
  int*   bsum   = (int*)carve(256 * sizeof(int));
  int*   col    = (int*)carve((size_t)ET * sizeof(int));
  float* out = (float*)d_out;

  // h1b = bf16(x @ W1), es1/ed1 fused.  [Nn,128]x[128,256], head=blockIdx.y
  gemm_att_kernel<64,64,16><<<dim3(cdiv_h(Nn,64), 4), 256, 0, stream>>>(
      x, W1, h1b, a_s1, a_d1, es1, ed1, Nn, 256, 128, 4);

  // CSR by dst (self-loops included)
  deg_init_kernel<<<cdiv_h(Nn + 1, 256), 256, 0, stream>>>(rowptr, Nn);
  hist_kernel<<<cdiv_h(E, 256), 256, 0, stream>>>(ei + E, E, rowptr);
  int nb = cdiv_h(Nn, 256);
  scan_blocks_kernel<<<nb, 256, 0, stream>>>(rowptr, Nn, bsum);
  scan_bsums_kernel<<<1, 256, 0, stream>>>(bsum, nb);
  scan_add_kernel<<<cdiv_h(Nn, 256), 256, 0, stream>>>(rowptr, Nn, bsum, ET);
  hipMemcpyAsync(cursor, rowptr, (size_t)Nn * sizeof(int), hipMemcpyDeviceToDevice, stream);
  scatter_kernel<<<cdiv_h(ET, 256), 256, 0, stream>>>(ei, E, Nn, cursor, col);

  // layer 1 aggregation + ELU
  agg1_kernel<<<cdiv_h(Nn, 4), 256, 0, stream>>>(h1b, es1, ed1, rowptr, col, b1, out1, Nn);

  // layer 2: h2b = bf16(out1 @ W2), es2/ed2 fused
  gemm_att_kernel<64,64,16><<<dim3(cdiv_h(Nn,64), 1), 256, 0, stream>>>(
      out1, W2, h2b, a_s2, a_d2, es2, ed2, Nn, 64, 256, 1);
  agg2_kernel<<<cdiv_h(Nn, 4), 256, 0, stream>>>(h2b, es2, ed2, rowptr, col, b2, Wo, bo, out, Nn);
}